// Round 9
// baseline (298.122 us; speedup 1.0000x reference)
//
#include <hip/hip_runtime.h>
#include <hip/hip_bf16.h>
#include <stdint.h>

typedef unsigned short u16;
typedef __bf16 bf16_t;
typedef bf16_t bf16x8 __attribute__((ext_vector_type(8)));
typedef float f32x4 __attribute__((ext_vector_type(4)));

#define DEV static __device__ __forceinline__

// Q pack scale: 0.125 * log2(e)  (softmax runs in exp2 domain)
#define QSCALE 0.18033688011112042f

// ---------- helpers ----------
DEV u16 f2b(float f) {
    __hip_bfloat16 h = __float2bfloat16(f);
    return __builtin_bit_cast(u16, h);
}

DEV bf16x8 ld_frag(const u16* p) {
    uint4 u = *reinterpret_cast<const uint4*>(p);
    return __builtin_bit_cast(bf16x8, u);
}

// exact-GELU via tanh identity (max abs err ~3e-4; margin is 0.07)
DEV float gelu(float v) {
    float y = 0.79788456080286536f * (v + 0.044715f * v * v * v);
    float e = __expf(-2.f * fabsf(y));
    float th = (1.f - e) / (1.f + e);
    th = copysignf(th, y);
    return 0.5f * v * (1.f + th);
}

DEV void gl_lds16(const u16* g, u16* l) {
    __builtin_amdgcn_global_load_lds(
        (const __attribute__((address_space(1))) void*)(uintptr_t)g,
        (__attribute__((address_space(3))) void*)(unsigned int)(uintptr_t)l,
        16, 0, 0);
}

// ---------- weight fp32 -> bf16 conversion ----------
struct ConvEnt { const float* s; u16* d; int n; };
struct ConvArgs { ConvEnt e[16]; };

__global__ __launch_bounds__(256) void k_conv(ConvArgs a) {
    const ConvEnt en = a.e[blockIdx.y];
    for (int i = (blockIdx.x * 256 + threadIdx.x) * 4; i < en.n; i += 256 * 256 * 4) {
        const float4 f = *reinterpret_cast<const float4*>(en.s + i);
        unsigned r0 = (unsigned)f2b(f.x) | ((unsigned)f2b(f.y) << 16);
        unsigned r1 = (unsigned)f2b(f.z) | ((unsigned)f2b(f.w) << 16);
        uint2 rr; rr.x = r0; rr.y = r1;
        *reinterpret_cast<uint2*>(en.d + i) = rr;
    }
}

// ---------- fused-bias concat ----------
struct CpyEnt { const float* s; float* d; };
struct CpyArgs { CpyEnt e[8]; };

__global__ __launch_bounds__(256) void k_cpyf(CpyArgs a) {
    const CpyEnt en = a.e[blockIdx.y];
    int i = blockIdx.x * 256 + threadIdx.x;
    en.d[i] = en.s[i];
}

// ---------- merged transpose in ----------
__global__ __launch_bounds__(256) void k_tin(const float* __restrict__ LL, const float* __restrict__ LH,
                                             float* __restrict__ llf, u16* __restrict__ llb,
                                             float* __restrict__ lhf, u16* __restrict__ lhb) {
    __shared__ float t[32][33];
    int z = blockIdx.z, b = z & 3;
    const float* in = (z < 4) ? LL : LH;
    float* of = (z < 4) ? llf : lhf;
    u16* ob = (z < 4) ? llb : lhb;
    int l0 = blockIdx.x * 32, d0 = blockIdx.y * 32;
    int tx = threadIdx.x, ty = threadIdx.y;
#pragma unroll
    for (int j = 0; j < 4; ++j) {
        int d = d0 + ty + j * 8;
        t[ty + j * 8][tx] = in[((size_t)b * 512 + d) * 1024 + l0 + tx];
    }
    __syncthreads();
#pragma unroll
    for (int j = 0; j < 4; ++j) {
        int l = l0 + ty + j * 8;
        float v = t[tx][ty + j * 8];
        size_t o = ((size_t)b * 1024 + l) * 512 + d0 + tx;
        of[o] = v;
        ob[o] = f2b(v);
    }
}

// ---------- merged transpose out ----------
__global__ __launch_bounds__(256) void k_tout(const float* __restrict__ y0, const float* __restrict__ y1,
                                              float* __restrict__ out) {
    __shared__ float t[32][33];
    int z = blockIdx.z, b = z & 3;
    const float* in = (z < 4) ? y0 : y1;
    float* o = out + ((z < 4) ? 0 : (size_t)4096 * 512);
    int l0 = blockIdx.x * 32, d0 = blockIdx.y * 32;
    int tx = threadIdx.x, ty = threadIdx.y;
#pragma unroll
    for (int j = 0; j < 4; ++j) {
        int l = l0 + ty + j * 8;
        t[ty + j * 8][tx] = in[((size_t)b * 1024 + l) * 512 + d0 + tx];
    }
    __syncthreads();
#pragma unroll
    for (int j = 0; j < 4; ++j) {
        int d = d0 + ty + j * 8;
        o[((size_t)b * 512 + d) * 1024 + l0 + tx] = t[tx][ty + j * 8];
    }
}

// ---------- energy mask (0 / -inf additive bias, exp2-domain safe) ----------
__global__ __launch_bounds__(256) void k_mask(const float* __restrict__ lh_s,
                                              const float* __restrict__ raw_tau,
                                              float* __restrict__ kbias) {
    int row = blockIdx.x * 4 + (threadIdx.x >> 6);
    int lane = threadIdx.x & 63;
    const float* p = lh_s + (size_t)row * 512 + lane * 8;
    float s = 0.f;
#pragma unroll
    for (int j = 0; j < 8; ++j) s += fabsf(p[j]);
#pragma unroll
    for (int m = 32; m >= 1; m >>= 1) s += __shfl_xor(s, m, 64);
    float tau = 1.f / (1.f + expf(-raw_tau[0]));
    if (lane == 0) kbias[row] = (s * (1.f / 512.f) > tau) ? 0.f : -__builtin_inff();
}

// ---------- LayerNorm ----------
__global__ __launch_bounds__(256) void k_ln(const float* __restrict__ a, const float* __restrict__ b,
                                            const float* __restrict__ c, const float* __restrict__ w,
                                            const float* __restrict__ bi,
                                            float* __restrict__ of, u16* __restrict__ ob) {
    int row = blockIdx.x * 4 + (threadIdx.x >> 6);
    int lane = threadIdx.x & 63;
    size_t base = (size_t)row * 512 + lane * 8;
    float x[8];
#pragma unroll
    for (int j = 0; j < 8; ++j) {
        float v = a[base + j] + b[base + j];
        if (c) v += c[base + j];
        x[j] = v;
    }
    float s = 0.f, s2 = 0.f;
#pragma unroll
    for (int j = 0; j < 8; ++j) { s += x[j]; s2 += x[j] * x[j]; }
#pragma unroll
    for (int m = 32; m >= 1; m >>= 1) { s += __shfl_xor(s, m, 64); s2 += __shfl_xor(s2, m, 64); }
    float mean = s * (1.f / 512.f);
    float var = s2 * (1.f / 512.f) - mean * mean;
    float rs = rsqrtf(var + 1e-5f);
#pragma unroll
    for (int j = 0; j < 8; ++j) {
        float y = (x[j] - mean) * rs * w[lane * 8 + j] + bi[lane * 8 + j];
        of[base + j] = y;
        ob[base + j] = f2b(y);
    }
}

// ---------- GEMM body (dbuf + T2 swizzle + XCD-bijective swizzle) ----------
struct GP {
    const u16* A; const u16* W; const float* bias; const float* res;
    float* Cf; u16* Cb; u16* Qp; u16* Kp; u16* Vt;
    int N, K, kB, vB, nwg, pack;
};

template <int BM, int BN, int GELU_ACT, int PACK>
DEV void gemm_body(u16* smem, const GP g, int orig, int M) {
    constexpr int BK = 64;
    u16* Al = smem;                    // [2][BM*BK]
    u16* Wl = smem + 2 * BM * BK;      // [2][BN*BK]
    int bid;
    {
        const int xcd = orig & 7, lin = orig >> 3;
        const int q = g.nwg >> 3, r = g.nwg & 7;
        bid = (xcd < r ? xcd * (q + 1) : r * (q + 1) + (xcd - r) * q) + lin;
    }
    const int K = g.K, N = g.N;
    const int nny = N / BN;
    const int m0 = (bid / nny) * BM, n0 = (bid % nny) * BN;

    const int t = threadIdx.x, w = t >> 6, l = t & 63;
    constexpr int FM = BM / 32, FN = BN / 32;
    const int wr = w >> 1, wc = w & 1;
    const int lq = l & 15, lg = l >> 4;
    f32x4 acc[FM][FN] = {};

    const int srow = l >> 3, schunk = l & 7;
    auto stage = [&](int kcol, int buf) {
#pragma unroll
        for (int i = 0; i < BM / 32; ++i) {
            const int row = i * 32 + w * 8 + srow;
            gl_lds16(g.A + (size_t)(m0 + row) * K + kcol + ((schunk ^ (row & 7)) * 8),
                     &Al[buf * BM * BK + (i * 32 + w * 8) * BK]);
        }
#pragma unroll
        for (int i = 0; i < BN / 32; ++i) {
            const int row = i * 32 + w * 8 + srow;
            gl_lds16(g.W + (size_t)(n0 + row) * K + kcol + ((schunk ^ (row & 7)) * 8),
                     &Wl[buf * BN * BK + (i * 32 + w * 8) * BK]);
        }
    };

    stage(0, 0);
    const int KT = K / BK;
    for (int kt = 0; kt < KT; ++kt) {
        const int cur = kt & 1;
        __syncthreads();
        if (kt + 1 < KT) stage((kt + 1) * BK, cur ^ 1);
#pragma unroll
        for (int s = 0; s < 2; ++s) {
            bf16x8 af[FM], bw[FN];
#pragma unroll
            for (int i = 0; i < FM; ++i) {
                const int row = wr * (BM / 2) + i * 16 + lq;
                af[i] = ld_frag(&Al[cur * BM * BK + row * BK + (((s * 4 + lg) ^ (row & 7)) * 8)]);
            }
#pragma unroll
            for (int j = 0; j < FN; ++j) {
                const int row = wc * (BN / 2) + j * 16 + lq;
                bw[j] = ld_frag(&Wl[cur * BN * BK + row * BK + (((s * 4 + lg) ^ (row & 7)) * 8)]);
            }
#pragma unroll
            for (int i = 0; i < FM; ++i)
#pragma unroll
                for (int j = 0; j < FN; ++j)
                    acc[i][j] = __builtin_amdgcn_mfma_f32_16x16x32_bf16(af[i], bw[j], acc[i][j], 0, 0, 0);
        }
    }

    if (PACK && g.pack && n0 >= g.vB) {
        // V pack: LDS transpose (swizzled) -> coalesced 16B row stores into Vt[bh][d][1024]
        u16* T = Al;
        constexpr int CH = BM / 8, CMASK = CH - 1, SH = (CH == 16) ? 4 : 3;
        __syncthreads();
#pragma unroll
        for (int i = 0; i < FM; ++i) {
#pragma unroll
            for (int j = 0; j < FN; ++j) {
                const int ni = wc * (BN / 2) + j * 16 + lq;
                const float bn = g.bias[n0 + ni];
#pragma unroll
                for (int r2 = 0; r2 < 4; ++r2) {
                    const int mi = wr * (BM / 2) + i * 16 + lg * 4 + r2;
                    T[ni * BM + (((mi >> 3) ^ (ni & CMASK)) * 8) + (mi & 7)] = f2b(acc[i][j][r2] + bn);
                }
            }
        }
        __syncthreads();
        const int bb = m0 >> 10, mloc = m0 & 1023;
        const int mc = t & CMASK, nib = t >> SH;
        constexpr int RPP = 256 / CH;
#pragma unroll
        for (int p2 = 0; p2 < BN / RPP; ++p2) {
            const int ni = nib + p2 * RPP;
            uint4 u = *reinterpret_cast<const uint4*>(&T[ni * BM + ((mc ^ (ni & CMASK)) * 8)]);
            const int d = n0 - g.vB + ni;
            *reinterpret_cast<uint4*>(
                &g.Vt[((size_t)(bb * 8 + (d >> 6)) * 64 + (d & 63)) * 1024 + mloc + mc * 8]) = u;
        }
        return;
    }

#pragma unroll
    for (int i = 0; i < FM; ++i) {
#pragma unroll
        for (int j = 0; j < FN; ++j) {
            const int n = n0 + wc * (BN / 2) + j * 16 + lq;
            const float bn = g.bias[n];
#pragma unroll
            for (int r2 = 0; r2 < 4; ++r2) {
                const int m = m0 + wr * (BM / 2) + i * 16 + lg * 4 + r2;
                float v = acc[i][j][r2] + bn;
                if (GELU_ACT) v = gelu(v);
                if (PACK && g.pack) {
                    const int bb = m >> 10, ll_ = m & 1023;
                    if (n >= g.kB) {
                        const int d = n - g.kB;
                        g.Kp[((size_t)(bb * 8 + (d >> 6)) * 1024 + ll_) * 64 + (d & 63)] = f2b(v);
                    } else {
                        g.Qp[((size_t)(bb * 8 + (n >> 6)) * 1024 + ll_) * 64 + (n & 63)] = f2b(v * QSCALE);
                    }
                } else {
                    size_t o = (size_t)m * N + n;
                    if (g.res) v += g.res[o];
                    if (g.Cf) g.Cf[o] = v;
                    if (g.Cb) g.Cb[o] = f2b(v);
                }
            }
        }
    }
}

template <int BM, int BN, int GELU_ACT, int PACK>
__global__ __launch_bounds__(256) void k_gemm(GP p0, GP p1, int M) {
    __shared__ alignas(16) u16 smem[2 * (BM + BN) * 64];
    GP g = (blockIdx.y == 0) ? p0 : p1;
    if ((int)blockIdx.x >= g.nwg) return;
    gemm_body<BM, BN, GELU_ACT, PACK>(smem, g, blockIdx.x, M);
}

// ---------- attention body: QBLK=128, exp2 softmax, deferred denom ----------
// needs 24576 u16 of smem. Q pre-scaled by QSCALE; kbias entries in {0,-inf}.
struct AT { const u16* Qp; const u16* Kp; const u16* Vt; u16* O; const float* kbias; };

DEV void attn_body(u16* smem, const AT a, int orig, int nwg) {
    constexpr int L = 1024;
    u16* Pl = smem + 16384;  // [128*64]
    const int t = threadIdx.x, w = t >> 6, l = t & 63;
    const int bid = (orig & 7) * (nwg >> 3) + (orig >> 3);
    const int bh = bid >> 3, q0 = (bid & 7) * 128;
    const int bz = bh >> 3, h = bh & 7;
    const int lq = l & 15, lg = l >> 4;
    const float* kb = a.kbias ? (a.kbias + (size_t)bz * L) : nullptr;

    bf16x8 qa[2][2];
#pragma unroll
    for (int i = 0; i < 2; ++i) {
        const u16* qp = a.Qp + ((size_t)bh * L + q0 + w * 32 + i * 16 + lq) * 64 + lg * 8;
        qa[i][0] = ld_frag(qp);
        qa[i][1] = ld_frag(qp + 32);
    }

    const int r0 = w * 16 + (l >> 3), r1 = r0 + 8, c = l & 7;
    const u16* Ksrc0 = a.Kp + (size_t)bh * L * 64 + (size_t)r0 * 64 + ((c ^ (r0 & 7)) * 8);
    const u16* Ksrc1 = a.Kp + (size_t)bh * L * 64 + (size_t)r1 * 64 + ((c ^ (r1 & 7)) * 8);
    const u16* Vsrc0 = a.Vt + (size_t)bh * 64 * L + (size_t)r0 * L + ((c ^ (r0 & 7)) * 8);
    const u16* Vsrc1 = a.Vt + (size_t)bh * 64 * L + (size_t)r1 * L + ((c ^ (r1 & 7)) * 8);

    auto stage = [&](int k0, int buf) {
        u16* Kb = smem + buf * 4096;
        u16* Vb = smem + 8192 + buf * 4096;
        gl_lds16(Ksrc0 + (size_t)k0 * 64, &Kb[(w * 16) * 64]);
        gl_lds16(Ksrc1 + (size_t)k0 * 64, &Kb[(w * 16 + 8) * 64]);
        gl_lds16(Vsrc0 + k0, &Vb[(w * 16) * 64]);
        gl_lds16(Vsrc1 + k0, &Vb[(w * 16 + 8) * 64]);
    };

    int addrA[4][2];
#pragma unroll
    for (int f = 0; f < 4; ++f) {
        int row = f * 16 + lq;
#pragma unroll
        for (int s = 0; s < 2; ++s) addrA[f][s] = row * 64 + (((s * 4 + lg) ^ (row & 7)) * 8);
    }
    int paddr[2][2], pwbase[2];
#pragma unroll
    for (int i = 0; i < 2; ++i) {
        const int prow = w * 32 + i * 16 + lq;
#pragma unroll
        for (int s = 0; s < 2; ++s) paddr[i][s] = prow * 64 + (((s * 4 + lg) ^ (prow & 7)) * 8);
        pwbase[i] = w * 32 + i * 16 + lg * 4;
    }

    f32x4 oacc[2][4] = {};
    float lrow[2][4] = {};

    stage(0, 0);
    for (int kt = 0; kt < 16; ++kt) {
        const int cur = kt & 1;
        u16* Kc = smem + cur * 4096;
        u16* Vc = smem + 8192 + cur * 4096;
        __syncthreads();
        if (kt + 1 < 16) stage((kt + 1) * 64, cur ^ 1);

        f32x4 sc[2][4];
#pragma unroll
        for (int f = 0; f < 4; ++f) {
            bf16x8 k0 = ld_frag(&Kc[addrA[f][0]]);
            bf16x8 k1 = ld_frag(&Kc[addrA[f][1]]);
#pragma unroll
            for (int i = 0; i < 2; ++i) {
                f32x4 acc = {};
                acc = __builtin_amdgcn_mfma_f32_16x16x32_bf16(qa[i][0], k0, acc, 0, 0, 0);
                acc = __builtin_amdgcn_mfma_f32_16x16x32_bf16(qa[i][1], k1, acc, 0, 0, 0);
                sc[i][f] = acc;
            }
        }
#pragma unroll
        for (int f = 0; f < 4; ++f) {
            float bv = kb ? kb[kt * 64 + f * 16 + lq] : 0.f;
#pragma unroll
            for (int i = 0; i < 2; ++i) {
#pragma unroll
                for (int r = 0; r < 4; ++r) {
                    float pv = exp2f(sc[i][f][r] + bv);
                    lrow[i][r] += pv;
                    const int prow = pwbase[i] + r;
                    Pl[prow * 64 + (((f * 2 + (lq >> 3)) ^ (prow & 7)) * 8) + (lq & 7)] = f2b(pv);
                }
            }
        }
        bf16x8 pa[2][2];
#pragma unroll
        for (int i = 0; i < 2; ++i) {
            pa[i][0] = ld_frag(&Pl[paddr[i][0]]);
            pa[i][1] = ld_frag(&Pl[paddr[i][1]]);
        }
#pragma unroll
        for (int db = 0; db < 4; ++db) {
            bf16x8 v0 = ld_frag(&Vc[addrA[db][0]]);
            bf16x8 v1 = ld_frag(&Vc[addrA[db][1]]);
#pragma unroll
            for (int i = 0; i < 2; ++i) {
                oacc[i][db] = __builtin_amdgcn_mfma_f32_16x16x32_bf16(pa[i][0], v0, oacc[i][db], 0, 0, 0);
                oacc[i][db] = __builtin_amdgcn_mfma_f32_16x16x32_bf16(pa[i][1], v1, oacc[i][db], 0, 0, 0);
            }
        }
    }
#pragma unroll
    for (int i = 0; i < 2; ++i)
#pragma unroll
        for (int r = 0; r < 4; ++r) {
            float v = lrow[i][r];
#pragma unroll
            for (int msk = 8; msk >= 1; msk >>= 1) v += __shfl_xor(v, msk, 16);
            lrow[i][r] = v;
        }
#pragma unroll
    for (int i = 0; i < 2; ++i) {
#pragma unroll
        for (int db = 0; db < 4; ++db) {
#pragma unroll
            for (int r = 0; r < 4; ++r) {
                float denom = lrow[i][r];
                float v = (denom > 0.f) ? oacc[i][db][r] / denom : 0.f;
                a.O[((size_t)bz * L + q0 + w * 32 + i * 16 + lg * 4 + r) * 512 + h * 64 + db * 16 + lq] = f2b(v);
            }
        }
    }
}

// ---------- fused attention + GEMM dispatch ----------
template <int BM, int BN, int GELU_ACT, int PACK>
__global__ __launch_bounds__(256) void k_fattn(AT a, GP g, int nAttn, int M) {
    constexpr int GS = 2 * (BM + BN) * 64;
    constexpr int SZ = (GS > 24576) ? GS : 24576;
    __shared__ alignas(16) u16 smem[SZ];
    if ((int)blockIdx.x < nAttn)
        attn_body(smem, a, blockIdx.x, nAttn);
    else
        gemm_body<BM, BN, GELU_ACT, PACK>(smem, g, blockIdx.x - nAttn, M);
}

// ---------- host ----------
extern "C" void kernel_launch(void* const* d_in, const int* in_sizes, int n_in,
                              void* d_out, int out_size, void* d_ws, size_t ws_size,
                              hipStream_t stream) {
    const int M = 4096;
    const float* LL = (const float*)d_in[0];
    const float* LH = (const float*)d_in[1];
    const float* raw_tau = (const float*)d_in[2];
    auto F = [&](int i) { return (const float*)d_in[i]; };
    const int BIG = 1 << 28;

    char* p = (char*)d_ws;
    auto alloc = [&](size_t bytes) { void* r = (void*)p; p += (bytes + 255) & ~(size_t)255; return r; };
    const size_t MDf = (size_t)M * 512 * 4, MDb = (size_t)M * 512 * 2;
    float* ll_s_f = (float*)alloc(MDf);
    float* lh_s_f = (float*)alloc(MDf);
    u16* ll_s_b = (u16*)alloc(MDb);
    u16* lh_s_b = (u16*)alloc(MDb);
    u16* Qp = (u16*)alloc(2 * MDb);
    u16* Kp = (u16*)alloc(2 * MDb);
    u16* Vt = (u16*)alloc(2 * MDb);
    u16* Cxb = (u16*)alloc(2 * MDb);
    float* ll_o_f = (float*)alloc(MDf);
    u16* ll_o_b = (u16*)alloc(MDb);
    float* lh_o_f = (float*)alloc(MDf);
    u16* lh_o_b = (u16*)alloc(MDb);
    float* cr_o_f = (float*)alloc(MDf);
    float* ln_f_ll = (float*)alloc(MDf);
    float* ln_f_lh = (float*)alloc(MDf);
    u16* ln_b = (u16*)alloc(MDb);
    u16* hb = (u16*)alloc((size_t)M * 2048 * 2);
    float* yf_ll = (float*)alloc(MDf);
    float* yf_lh = (float*)alloc(MDf);
    float* kbias = (float*)alloc(4096 * 4);
    float* bqkv_ll = (float*)alloc(1536 * 4);
    float* bqkv_lh = (float*)alloc(1536 * 4);
    float* bkv_cr = (float*)alloc(1024 * 4);
    const size_t WDD = (size_t)262144;
    u16* wqkv_ll = (u16*)alloc(3 * WDD * 2);
    u16* wqkv_lh = (u16*)alloc(3 * WDD * 2);
    u16* wkv_cr = (u16*)alloc(2 * WDD * 2);
    u16* wq_cr = (u16*)alloc(WDD * 2);
    u16* wo_ll = (u16*)alloc(WDD * 2);
    u16* wo_lh = (u16*)alloc(WDD * 2);
    u16* wo_cr = (u16*)alloc(WDD * 2);
    u16* wm[4];
    for (int i = 0; i < 4; ++i) wm[i] = (u16*)alloc((size_t)1048576 * 2);

    const size_t SET = (size_t)4 * 8 * 1024 * 64;

    ConvArgs ca;
    ca.e[0] = {F(3), wqkv_ll, (int)WDD};
    ca.e[1] = {F(5), wqkv_ll + WDD, (int)WDD};
    ca.e[2] = {F(7), wqkv_ll + 2 * WDD, (int)WDD};
    ca.e[3] = {F(11), wqkv_lh, (int)WDD};
    ca.e[4] = {F(13), wqkv_lh + WDD, (int)WDD};
    ca.e[5] = {F(15), wqkv_lh + 2 * WDD, (int)WDD};
    ca.e[6] = {F(19), wq_cr, (int)WDD};
    ca.e[7] = {F(21), wkv_cr, (int)WDD};
    ca.e[8] = {F(23), wkv_cr + WDD, (int)WDD};
    ca.e[9] = {F(9), wo_ll, (int)WDD};
    ca.e[10] = {F(17), wo_lh, (int)WDD};
    ca.e[11] = {F(25), wo_cr, (int)WDD};
    ca.e[12] = {F(27), wm[0], 1048576};
    ca.e[13] = {F(29), wm[1], 1048576};
    ca.e[14] = {F(31), wm[2], 1048576};
    ca.e[15] = {F(33), wm[3], 1048576};
    k_conv<<<dim3(256, 16), 256, 0, stream>>>(ca);

    CpyArgs cp;
    cp.e[0] = {F(4), bqkv_ll};
    cp.e[1] = {F(6), bqkv_ll + 512};
    cp.e[2] = {F(8), bqkv_ll + 1024};
    cp.e[3] = {F(12), bqkv_lh};
    cp.e[4] = {F(14), bqkv_lh + 512};
    cp.e[5] = {F(16), bqkv_lh + 1024};
    cp.e[6] = {F(22), bkv_cr};
    cp.e[7] = {F(24), bkv_cr + 512};
    k_cpyf<<<dim3(2, 8), 256, 0, stream>>>(cp);

    k_tin<<<dim3(32, 16, 8), dim3(32, 8), 0, stream>>>(LL, LH, ll_s_f, ll_s_b, lh_s_f, lh_s_b);
    k_mask<<<dim3(1024), 256, 0, stream>>>(lh_s_f, raw_tau, kbias);

    auto gp = [&](const u16* A, const u16* W, const float* bias, int N, int K, int nwg) {
        GP g = {};
        g.A = A; g.W = W; g.bias = bias; g.N = N; g.K = K; g.nwg = nwg;
        g.kB = BIG; g.vB = BIG; g.pack = 0;
        return g;
    };

    // 1) qkv_ll (128x128, PACK set0)
    {
        GP a = gp(ll_s_b, wqkv_ll, bqkv_ll, 1536, 512, 384);
        a.pack = 1; a.kB = 512; a.vB = 1024; a.Qp = Qp; a.Kp = Kp; a.Vt = Vt;
        k_gemm<128, 128, 0, 1><<<dim3(384, 1), 256, 0, stream>>>(a, a, M);
    }
    // 2) fused: attn_ll (256) + qkv_lh (384, PACK set1)
    {
        AT at = {Qp, Kp, Vt, Cxb, nullptr};
        GP g = gp(lh_s_b, wqkv_lh, bqkv_lh, 1536, 512, 384);
        g.pack = 1; g.kB = 512; g.vB = 1024; g.Qp = Qp + SET; g.Kp = Kp + SET; g.Vt = Vt + SET;
        k_fattn<128, 128, 0, 1><<<dim3(640), 256, 0, stream>>>(at, g, 256, M);
    }
    // 3) fused: attn_lh (256, biased) + wo_ll (512)
    {
        AT at = {Qp + SET, Kp + SET, Vt + SET, Cxb + SET, kbias};
        GP g = gp(Cxb, wo_ll, F(10), 512, 512, 512);
        g.Cf = ll_o_f; g.Cb = ll_o_b;
        k_fattn<64, 64, 0, 1><<<dim3(768), 256, 0, stream>>>(at, g, 256, M);
    }
    // 4) pair: wo_lh + crQ (PACK)
    {
        GP a = gp(Cxb + SET, wo_lh, F(18), 512, 512, 512);
        a.Cf = lh_o_f; a.Cb = lh_o_b;
        GP b = gp(ll_o_b, wq_cr, F(20), 512, 512, 512);
        b.pack = 1; b.Qp = Qp;  // kB=vB=BIG -> all Q
        k_gemm<64, 64, 0, 1><<<dim3(512, 2), 256, 0, stream>>>(a, b, M);
    }
    k_ln<<<dim3(1024), 256, 0, stream>>>(lh_s_f, lh_o_f, nullptr, F(37), F(38), ln_f_lh, ln_b);
    // 5) crKV (PACK)
    {
        GP a = gp(lh_o_b, wkv_cr, bkv_cr, 1024, 512, 1024);
        a.pack = 1; a.kB = 0; a.vB = 512; a.Kp = Kp; a.Vt = Vt;
        k_gemm<64, 64, 0, 1><<<dim3(1024, 1), 256, 0, stream>>>(a, a, M);
    }
    // 6) fused: cross attn (256) + mlp_lh_up (512, GELU)
    {
        AT at = {Qp, Kp, Vt, Cxb, nullptr};
        GP g = gp(ln_b, wm[2], F(32), 2048, 512, 512);
        g.Cb = hb;
        k_fattn<128, 128, 1, 0><<<dim3(768), 256, 0, stream>>>(at, g, 256, M);
    }
    // 7) pair: wo_cr + mlp_lh_down
    {
        GP a = gp(Cxb, wo_cr, F(26), 512, 512, 512);
        a.Cf = cr_o_f;
        GP b = gp(hb, wm[3], F(34), 512, 2048, 512);
        b.Cf = yf_lh; b.res = ln_f_lh;
        k_gemm<64, 64, 0, 0><<<dim3(512, 2), 256, 0, stream>>>(a, b, M);
    }
    k_ln<<<dim3(1024), 256, 0, stream>>>(ll_s_f, ll_o_f, cr_o_f, F(35), F(36), ln_f_ll, ln_b);
    // 8) mlp_ll_up
    {
        GP a = gp(ln_b, wm[0], F(28), 2048, 512, 512);
        a.Cb = hb;
        k_gemm<128, 128, 1, 0><<<dim3(512, 1), 256, 0, stream>>>(a, a, M);
    }
    // 9) mlp_ll_down
    {
        GP a = gp(hb, wm[1], F(30), 512, 2048, 512);
        a.Cf = yf_ll; a.res = ln_f_ll;
        k_gemm<64, 64, 0, 0><<<dim3(512, 1), 256, 0, stream>>>(a, a, M);
    }
    k_tout<<<dim3(32, 16, 8), dim3(32, 8), 0, stream>>>(yf_ll, yf_lh, (float*)d_out);
}

// Round 10
// 285.669 us; speedup vs baseline: 1.0436x; 1.0436x over previous
//
#include <hip/hip_runtime.h>
#include <hip/hip_bf16.h>
#include <stdint.h>

typedef unsigned short u16;
typedef __bf16 bf16_t;
typedef bf16_t bf16x8 __attribute__((ext_vector_type(8)));
typedef float f32x4 __attribute__((ext_vector_type(4)));

#define DEV static __device__ __forceinline__

// Q pack scale: 0.125 * log2(e)  (softmax runs in exp2 domain)
#define QSCALE 0.18033688011112042f

// ---------- helpers ----------
DEV u16 f2b(float f) {
    __hip_bfloat16 h = __float2bfloat16(f);
    return __builtin_bit_cast(u16, h);
}

DEV bf16x8 ld_frag(const u16* p) {
    uint4 u = *reinterpret_cast<const uint4*>(p);
    return __builtin_bit_cast(bf16x8, u);
}

// exact-GELU via tanh identity (max abs err ~3e-4; margin is 0.07)
DEV float gelu(float v) {
    float y = 0.79788456080286536f * (v + 0.044715f * v * v * v);
    float e = __expf(-2.f * fabsf(y));
    float th = (1.f - e) / (1.f + e);
    th = copysignf(th, y);
    return 0.5f * v * (1.f + th);
}

DEV void gl_lds16(const u16* g, u16* l) {
    __builtin_amdgcn_global_load_lds(
        (const __attribute__((address_space(1))) void*)(uintptr_t)g,
        (__attribute__((address_space(3))) void*)(unsigned int)(uintptr_t)l,
        16, 0, 0);
}

// ---------- weight fp32 -> bf16 conversion ----------
struct ConvEnt { const float* s; u16* d; int n; };
struct ConvArgs { ConvEnt e[16]; };

__global__ __launch_bounds__(256) void k_conv(ConvArgs a) {
    const ConvEnt en = a.e[blockIdx.y];
    for (int i = (blockIdx.x * 256 + threadIdx.x) * 4; i < en.n; i += 256 * 256 * 4) {
        const float4 f = *reinterpret_cast<const float4*>(en.s + i);
        unsigned r0 = (unsigned)f2b(f.x) | ((unsigned)f2b(f.y) << 16);
        unsigned r1 = (unsigned)f2b(f.z) | ((unsigned)f2b(f.w) << 16);
        uint2 rr; rr.x = r0; rr.y = r1;
        *reinterpret_cast<uint2*>(en.d + i) = rr;
    }
}

// ---------- fused-bias concat ----------
struct CpyEnt { const float* s; float* d; };
struct CpyArgs { CpyEnt e[8]; };

__global__ __launch_bounds__(256) void k_cpyf(CpyArgs a) {
    const CpyEnt en = a.e[blockIdx.y];
    int i = blockIdx.x * 256 + threadIdx.x;
    en.d[i] = en.s[i];
}

// ---------- merged transpose in ----------
__global__ __launch_bounds__(256) void k_tin(const float* __restrict__ LL, const float* __restrict__ LH,
                                             float* __restrict__ llf, u16* __restrict__ llb,
                                             float* __restrict__ lhf, u16* __restrict__ lhb) {
    __shared__ float t[32][33];
    int z = blockIdx.z, b = z & 3;
    const float* in = (z < 4) ? LL : LH;
    float* of = (z < 4) ? llf : lhf;
    u16* ob = (z < 4) ? llb : lhb;
    int l0 = blockIdx.x * 32, d0 = blockIdx.y * 32;
    int tx = threadIdx.x, ty = threadIdx.y;
#pragma unroll
    for (int j = 0; j < 4; ++j) {
        int d = d0 + ty + j * 8;
        t[ty + j * 8][tx] = in[((size_t)b * 512 + d) * 1024 + l0 + tx];
    }
    __syncthreads();
#pragma unroll
    for (int j = 0; j < 4; ++j) {
        int l = l0 + ty + j * 8;
        float v = t[tx][ty + j * 8];
        size_t o = ((size_t)b * 1024 + l) * 512 + d0 + tx;
        of[o] = v;
        ob[o] = f2b(v);
    }
}

// ---------- merged transpose out ----------
__global__ __launch_bounds__(256) void k_tout(const float* __restrict__ y0, const float* __restrict__ y1,
                                              float* __restrict__ out) {
    __shared__ float t[32][33];
    int z = blockIdx.z, b = z & 3;
    const float* in = (z < 4) ? y0 : y1;
    float* o = out + ((z < 4) ? 0 : (size_t)4096 * 512);
    int l0 = blockIdx.x * 32, d0 = blockIdx.y * 32;
    int tx = threadIdx.x, ty = threadIdx.y;
#pragma unroll
    for (int j = 0; j < 4; ++j) {
        int l = l0 + ty + j * 8;
        t[ty + j * 8][tx] = in[((size_t)b * 1024 + l) * 512 + d0 + tx];
    }
    __syncthreads();
#pragma unroll
    for (int j = 0; j < 4; ++j) {
        int d = d0 + ty + j * 8;
        o[((size_t)b * 512 + d) * 1024 + l0 + tx] = t[tx][ty + j * 8];
    }
}

// ---------- energy mask (0 / -inf additive bias, exp2-domain safe) ----------
__global__ __launch_bounds__(256) void k_mask(const float* __restrict__ lh_s,
                                              const float* __restrict__ raw_tau,
                                              float* __restrict__ kbias) {
    int row = blockIdx.x * 4 + (threadIdx.x >> 6);
    int lane = threadIdx.x & 63;
    const float* p = lh_s + (size_t)row * 512 + lane * 8;
    float s = 0.f;
#pragma unroll
    for (int j = 0; j < 8; ++j) s += fabsf(p[j]);
#pragma unroll
    for (int m = 32; m >= 1; m >>= 1) s += __shfl_xor(s, m, 64);
    float tau = 1.f / (1.f + expf(-raw_tau[0]));
    if (lane == 0) kbias[row] = (s * (1.f / 512.f) > tau) ? 0.f : -__builtin_inff();
}

// ---------- LayerNorm ----------
__global__ __launch_bounds__(256) void k_ln(const float* __restrict__ a, const float* __restrict__ b,
                                            const float* __restrict__ c, const float* __restrict__ w,
                                            const float* __restrict__ bi,
                                            float* __restrict__ of, u16* __restrict__ ob) {
    int row = blockIdx.x * 4 + (threadIdx.x >> 6);
    int lane = threadIdx.x & 63;
    size_t base = (size_t)row * 512 + lane * 8;
    float x[8];
#pragma unroll
    for (int j = 0; j < 8; ++j) {
        float v = a[base + j] + b[base + j];
        if (c) v += c[base + j];
        x[j] = v;
    }
    float s = 0.f, s2 = 0.f;
#pragma unroll
    for (int j = 0; j < 8; ++j) { s += x[j]; s2 += x[j] * x[j]; }
#pragma unroll
    for (int m = 32; m >= 1; m >>= 1) { s += __shfl_xor(s, m, 64); s2 += __shfl_xor(s2, m, 64); }
    float mean = s * (1.f / 512.f);
    float var = s2 * (1.f / 512.f) - mean * mean;
    float rs = rsqrtf(var + 1e-5f);
#pragma unroll
    for (int j = 0; j < 8; ++j) {
        float y = (x[j] - mean) * rs * w[lane * 8 + j] + bi[lane * 8 + j];
        of[base + j] = y;
        ob[base + j] = f2b(y);
    }
}

// ---------- paired bf16 MFMA GEMM (blockIdx.y selects descriptor) ----------
struct GP {
    const u16* A; const u16* W; const float* bias; const float* res;
    float* Cf; u16* Cb; u16* Qp; u16* Kp; u16* Vt;
    int N, K, kB, vB, nwg;
};

template <int BM, int BN, int GELU_ACT, int PACK>
__global__ __launch_bounds__(256) void k_gemm(GP p0, GP p1, int M) {
    constexpr int BK = 64;
    __shared__ alignas(16) u16 Al[2][BM * BK];
    __shared__ alignas(16) u16 Wl[2][BN * BK];
    GP g = (blockIdx.y == 0) ? p0 : p1;
    const int orig = blockIdx.x;
    if (orig >= g.nwg) return;
    int bid;
    {
        const int xcd = orig & 7, lin = orig >> 3;
        const int q = g.nwg >> 3, r = g.nwg & 7;
        bid = (xcd < r ? xcd * (q + 1) : r * (q + 1) + (xcd - r) * q) + lin;
    }
    const int K = g.K, N = g.N;
    const int nny = N / BN;
    const int m0 = (bid / nny) * BM, n0 = (bid % nny) * BN;

    const int t = threadIdx.x, w = t >> 6, l = t & 63;
    constexpr int FM = BM / 32, FN = BN / 32;
    const int wr = w >> 1, wc = w & 1;
    const int lq = l & 15, lg = l >> 4;
    f32x4 acc[FM][FN] = {};

    const int srow = l >> 3, schunk = l & 7;
    auto stage = [&](int kcol, int buf) {
#pragma unroll
        for (int i = 0; i < BM / 32; ++i) {
            const int row = i * 32 + w * 8 + srow;
            gl_lds16(g.A + (size_t)(m0 + row) * K + kcol + ((schunk ^ (row & 7)) * 8),
                     &Al[buf][(i * 32 + w * 8) * BK]);
        }
#pragma unroll
        for (int i = 0; i < BN / 32; ++i) {
            const int row = i * 32 + w * 8 + srow;
            gl_lds16(g.W + (size_t)(n0 + row) * K + kcol + ((schunk ^ (row & 7)) * 8),
                     &Wl[buf][(i * 32 + w * 8) * BK]);
        }
    };

    stage(0, 0);
    const int KT = K / BK;
    for (int kt = 0; kt < KT; ++kt) {
        const int cur = kt & 1;
        __syncthreads();
        if (kt + 1 < KT) stage((kt + 1) * BK, cur ^ 1);
#pragma unroll
        for (int s = 0; s < 2; ++s) {
            bf16x8 af[FM], bw[FN];
#pragma unroll
            for (int i = 0; i < FM; ++i) {
                const int row = wr * (BM / 2) + i * 16 + lq;
                af[i] = ld_frag(&Al[cur][row * BK + (((s * 4 + lg) ^ (row & 7)) * 8)]);
            }
#pragma unroll
            for (int j = 0; j < FN; ++j) {
                const int row = wc * (BN / 2) + j * 16 + lq;
                bw[j] = ld_frag(&Wl[cur][row * BK + (((s * 4 + lg) ^ (row & 7)) * 8)]);
            }
#pragma unroll
            for (int i = 0; i < FM; ++i)
#pragma unroll
                for (int j = 0; j < FN; ++j)
                    acc[i][j] = __builtin_amdgcn_mfma_f32_16x16x32_bf16(af[i], bw[j], acc[i][j], 0, 0, 0);
        }
    }

    if (PACK && n0 >= g.vB) {
        u16* T = (u16*)Al;
        constexpr int CH = BM / 8, CMASK = CH - 1, SH = (CH == 16) ? 4 : 3;
        __syncthreads();
#pragma unroll
        for (int i = 0; i < FM; ++i) {
#pragma unroll
            for (int j = 0; j < FN; ++j) {
                const int ni = wc * (BN / 2) + j * 16 + lq;
                const float bn = g.bias[n0 + ni];
#pragma unroll
                for (int r2 = 0; r2 < 4; ++r2) {
                    const int mi = wr * (BM / 2) + i * 16 + lg * 4 + r2;
                    T[ni * BM + (((mi >> 3) ^ (ni & CMASK)) * 8) + (mi & 7)] = f2b(acc[i][j][r2] + bn);
                }
            }
        }
        __syncthreads();
        const int bb = m0 >> 10, mloc = m0 & 1023;
        const int mc = t & CMASK, nib = t >> SH;
        constexpr int RPP = 256 / CH;
#pragma unroll
        for (int p2 = 0; p2 < BN / RPP; ++p2) {
            const int ni = nib + p2 * RPP;
            uint4 u = *reinterpret_cast<const uint4*>(&T[ni * BM + ((mc ^ (ni & CMASK)) * 8)]);
            const int d = n0 - g.vB + ni;
            *reinterpret_cast<uint4*>(
                &g.Vt[((size_t)(bb * 8 + (d >> 6)) * 64 + (d & 63)) * 1024 + mloc + mc * 8]) = u;
        }
        return;
    }

#pragma unroll
    for (int i = 0; i < FM; ++i) {
#pragma unroll
        for (int j = 0; j < FN; ++j) {
            const int n = n0 + wc * (BN / 2) + j * 16 + lq;
            const float bn = g.bias[n];
#pragma unroll
            for (int r2 = 0; r2 < 4; ++r2) {
                const int m = m0 + wr * (BM / 2) + i * 16 + lg * 4 + r2;
                float v = acc[i][j][r2] + bn;
                if (GELU_ACT) v = gelu(v);
                if (PACK) {
                    const int bb = m >> 10, ll_ = m & 1023;
                    if (n >= g.kB) {
                        const int d = n - g.kB;
                        g.Kp[((size_t)(bb * 8 + (d >> 6)) * 1024 + ll_) * 64 + (d & 63)] = f2b(v);
                    } else {
                        g.Qp[((size_t)(bb * 8 + (n >> 6)) * 1024 + ll_) * 64 + (n & 63)] = f2b(v * QSCALE);
                    }
                } else {
                    size_t o = (size_t)m * N + n;
                    if (g.res) v += g.res[o];
                    if (g.Cf) g.Cf[o] = v;
                    if (g.Cb) g.Cb[o] = f2b(v);
                }
            }
        }
    }
}

// ---------- K-split flash attention: QBLK=128, exp2 softmax, partial (num,den) out ----------
// grid = items*2; block bid: item=bid>>1, half=bid&1 processes KV tiles [half*8, half*8+8).
// Writes numW[bid][128][64] (f32, pre-division) and denW[bid][128].
__global__ __launch_bounds__(256) void k_attnK(const u16* __restrict__ Qp, const u16* __restrict__ Kp,
                                               const u16* __restrict__ Vtp,
                                               float* __restrict__ numW, float* __restrict__ denW,
                                               const float* __restrict__ kbias, int nwg) {
    constexpr int L = 1024;
    __shared__ alignas(16) u16 Kl[2][64 * 64];
    __shared__ alignas(16) u16 Vl[2][64 * 64];
    __shared__ alignas(16) u16 Pl[128 * 64];
    const int t = threadIdx.x, w = t >> 6, l = t & 63;
    const int bid = ((int)blockIdx.x & 7) * (nwg >> 3) + ((int)blockIdx.x >> 3);
    const int item = bid >> 1, half = bid & 1;
    const int bh = item >> 3, q0 = (item & 7) * 128;
    const int bz = bh >> 3, h = bh & 7;
    (void)h;
    const int lq = l & 15, lg = l >> 4;
    const float* kb = (kbias != nullptr && bz >= 4) ? (kbias + (size_t)(bz - 4) * L) : nullptr;
    const int kbase = half * 512;  // element offset of this half's KV range

    bf16x8 qa[2][2];
#pragma unroll
    for (int i = 0; i < 2; ++i) {
        const u16* qp = Qp + ((size_t)bh * L + q0 + w * 32 + i * 16 + lq) * 64 + lg * 8;
        qa[i][0] = ld_frag(qp);
        qa[i][1] = ld_frag(qp + 32);
    }

    const int r0 = w * 16 + (l >> 3), r1 = r0 + 8, c = l & 7;
    const u16* Ksrc0 = Kp + (size_t)bh * L * 64 + (size_t)r0 * 64 + ((c ^ (r0 & 7)) * 8);
    const u16* Ksrc1 = Kp + (size_t)bh * L * 64 + (size_t)r1 * 64 + ((c ^ (r1 & 7)) * 8);
    const u16* Vsrc0 = Vtp + (size_t)bh * 64 * L + (size_t)r0 * L + ((c ^ (r0 & 7)) * 8);
    const u16* Vsrc1 = Vtp + (size_t)bh * 64 * L + (size_t)r1 * L + ((c ^ (r1 & 7)) * 8);

    auto stage = [&](int k0, int buf) {
        gl_lds16(Ksrc0 + (size_t)k0 * 64, &Kl[buf][(w * 16) * 64]);
        gl_lds16(Ksrc1 + (size_t)k0 * 64, &Kl[buf][(w * 16 + 8) * 64]);
        gl_lds16(Vsrc0 + k0, &Vl[buf][(w * 16) * 64]);
        gl_lds16(Vsrc1 + k0, &Vl[buf][(w * 16 + 8) * 64]);
    };

    int addrA[4][2];
#pragma unroll
    for (int f = 0; f < 4; ++f) {
        int row = f * 16 + lq;
#pragma unroll
        for (int s = 0; s < 2; ++s) addrA[f][s] = row * 64 + (((s * 4 + lg) ^ (row & 7)) * 8);
    }
    int paddr[2][2], pwbase[2];
#pragma unroll
    for (int i = 0; i < 2; ++i) {
        const int prow = w * 32 + i * 16 + lq;
#pragma unroll
        for (int s = 0; s < 2; ++s) paddr[i][s] = prow * 64 + (((s * 4 + lg) ^ (prow & 7)) * 8);
        pwbase[i] = w * 32 + i * 16 + lg * 4;
    }

    f32x4 oacc[2][4] = {};
    float lrow[2][4] = {};

    stage(kbase, 0);
    for (int kt = 0; kt < 8; ++kt) {
        const int cur = kt & 1;
        __syncthreads();
        if (kt + 1 < 8) stage(kbase + (kt + 1) * 64, cur ^ 1);

        f32x4 sc[2][4];
        __builtin_amdgcn_s_setprio(1);
#pragma unroll
        for (int f = 0; f < 4; ++f) {
            bf16x8 k0 = ld_frag(&Kl[cur][addrA[f][0]]);
            bf16x8 k1 = ld_frag(&Kl[cur][addrA[f][1]]);
#pragma unroll
            for (int i = 0; i < 2; ++i) {
                f32x4 a = {};
                a = __builtin_amdgcn_mfma_f32_16x16x32_bf16(qa[i][0], k0, a, 0, 0, 0);
                a = __builtin_amdgcn_mfma_f32_16x16x32_bf16(qa[i][1], k1, a, 0, 0, 0);
                sc[i][f] = a;
            }
        }
        __builtin_amdgcn_s_setprio(0);
#pragma unroll
        for (int f = 0; f < 4; ++f) {
            float bv = kb ? kb[kbase + kt * 64 + f * 16 + lq] : 0.f;
#pragma unroll
            for (int i = 0; i < 2; ++i) {
#pragma unroll
                for (int r = 0; r < 4; ++r) {
                    float pv = exp2f(sc[i][f][r] + bv);
                    lrow[i][r] += pv;
                    const int prow = pwbase[i] + r;
                    Pl[prow * 64 + (((f * 2 + (lq >> 3)) ^ (prow & 7)) * 8) + (lq & 7)] = f2b(pv);
                }
            }
        }
        bf16x8 pa[2][2];
#pragma unroll
        for (int i = 0; i < 2; ++i) {
            pa[i][0] = ld_frag(&Pl[paddr[i][0]]);
            pa[i][1] = ld_frag(&Pl[paddr[i][1]]);
        }
        __builtin_amdgcn_s_setprio(1);
#pragma unroll
        for (int db = 0; db < 4; ++db) {
            bf16x8 v0 = ld_frag(&Vl[cur][addrA[db][0]]);
            bf16x8 v1 = ld_frag(&Vl[cur][addrA[db][1]]);
#pragma unroll
            for (int i = 0; i < 2; ++i) {
                oacc[i][db] = __builtin_amdgcn_mfma_f32_16x16x32_bf16(pa[i][0], v0, oacc[i][db], 0, 0, 0);
                oacc[i][db] = __builtin_amdgcn_mfma_f32_16x16x32_bf16(pa[i][1], v1, oacc[i][db], 0, 0, 0);
            }
        }
        __builtin_amdgcn_s_setprio(0);
    }
    // reduce den partials across the 16 lq lanes
#pragma unroll
    for (int i = 0; i < 2; ++i)
#pragma unroll
        for (int r = 0; r < 4; ++r) {
            float v = lrow[i][r];
#pragma unroll
            for (int msk = 8; msk >= 1; msk >>= 1) v += __shfl_xor(v, msk, 16);
            lrow[i][r] = v;
        }
    // write partials (slot keyed by logical bid)
    float* nw = numW + (size_t)bid * 8192;
#pragma unroll
    for (int i = 0; i < 2; ++i) {
#pragma unroll
        for (int db = 0; db < 4; ++db) {
#pragma unroll
            for (int r = 0; r < 4; ++r) {
                nw[(pwbase[i] + r) * 64 + db * 16 + lq] = oacc[i][db][r];
            }
        }
    }
    if (lq == 0) {
#pragma unroll
        for (int i = 0; i < 2; ++i)
#pragma unroll
            for (int r = 0; r < 4; ++r) denW[(size_t)bid * 128 + pwbase[i] + r] = lrow[i][r];
    }
}

// ---------- combine: O = (num0+num1)/(den0+den1), packed [bz][l][h*64+d] bf16 ----------
__global__ __launch_bounds__(256) void k_comb(const float* __restrict__ numW,
                                              const float* __restrict__ denW,
                                              u16* __restrict__ O) {
    const int item = blockIdx.x, t = threadIdx.x;
    const int bh = item >> 3, q0 = (item & 7) * 128;
    const int bz = bh >> 3, h = bh & 7;
    const float4* n0 = (const float4*)(numW + (size_t)(item * 2) * 8192);
    const float4* n1 = (const float4*)(numW + (size_t)(item * 2 + 1) * 8192);
    const float* d0 = denW + (size_t)(item * 2) * 128;
    const float* d1 = denW + (size_t)(item * 2 + 1) * 128;
#pragma unroll
    for (int e = 0; e < 8; ++e) {
        const int g = e * 256 + t;        // float4 granule: 2048 per item
        const int row = g >> 4, c4 = (g & 15) * 4;
        float4 a = n0[g], b = n1[g];
        float den = d0[row] + d1[row];
        float inv = (den > 0.f) ? 1.f / den : 0.f;
        u16 o4[4];
        o4[0] = f2b((a.x + b.x) * inv);
        o4[1] = f2b((a.y + b.y) * inv);
        o4[2] = f2b((a.z + b.z) * inv);
        o4[3] = f2b((a.w + b.w) * inv);
        *reinterpret_cast<uint2*>(&O[((size_t)bz * 1024 + q0 + row) * 512 + h * 64 + c4]) =
            *reinterpret_cast<uint2*>(o4);
    }
}

// ---------- host ----------
extern "C" void kernel_launch(void* const* d_in, const int* in_sizes, int n_in,
                              void* d_out, int out_size, void* d_ws, size_t ws_size,
                              hipStream_t stream) {
    const int M = 4096;
    const float* LL = (const float*)d_in[0];
    const float* LH = (const float*)d_in[1];
    const float* raw_tau = (const float*)d_in[2];
    auto F = [&](int i) { return (const float*)d_in[i]; };
    const int BIG = 1 << 28;

    char* p = (char*)d_ws;
    auto alloc = [&](size_t bytes) { void* r = (void*)p; p += (bytes + 255) & ~(size_t)255; return r; };
    const size_t MDf = (size_t)M * 512 * 4, MDb = (size_t)M * 512 * 2;
    float* ll_s_f = (float*)alloc(MDf);
    float* lh_s_f = (float*)alloc(MDf);
    u16* ll_s_b = (u16*)alloc(MDb);
    u16* lh_s_b = (u16*)alloc(MDb);
    u16* Qp = (u16*)alloc(2 * MDb);
    u16* Kp = (u16*)alloc(2 * MDb);
    u16* Vt = (u16*)alloc(2 * MDb);
    u16* Cxb = (u16*)alloc(2 * MDb);
    float* ll_o_f = (float*)alloc(MDf);
    u16* ll_o_b = (u16*)alloc(MDb);
    float* lh_o_f = (float*)alloc(MDf);
    u16* lh_o_b = (u16*)alloc(MDb);
    float* cr_o_f = (float*)alloc(MDf);
    float* ln_f_ll = (float*)alloc(MDf);
    float* ln_f_lh = (float*)alloc(MDf);
    u16* ln_b = (u16*)alloc(MDb);
    u16* hb = (u16*)alloc((size_t)M * 2048 * 2);
    float* yf_ll = (float*)alloc(MDf);
    float* yf_lh = (float*)alloc(MDf);
    float* kbias = (float*)alloc(4096 * 4);
    float* bqkv_ll = (float*)alloc(1536 * 4);
    float* bqkv_lh = (float*)alloc(1536 * 4);
    float* bkv_cr = (float*)alloc(1024 * 4);
    float* numW = (float*)alloc((size_t)1024 * 8192 * 4);
    float* denW = (float*)alloc((size_t)1024 * 128 * 4);
    const size_t WDD = (size_t)262144;
    u16* wqkv_ll = (u16*)alloc(3 * WDD * 2);
    u16* wqkv_lh = (u16*)alloc(3 * WDD * 2);
    u16* wkv_cr = (u16*)alloc(2 * WDD * 2);
    u16* wq_cr = (u16*)alloc(WDD * 2);
    u16* wo_ll = (u16*)alloc(WDD * 2);
    u16* wo_lh = (u16*)alloc(WDD * 2);
    u16* wo_cr = (u16*)alloc(WDD * 2);
    u16* wm[4];
    for (int i = 0; i < 4; ++i) wm[i] = (u16*)alloc((size_t)1048576 * 2);

    const size_t SET = (size_t)4 * 8 * 1024 * 64;

    ConvArgs ca;
    ca.e[0] = {F(3), wqkv_ll, (int)WDD};
    ca.e[1] = {F(5), wqkv_ll + WDD, (int)WDD};
    ca.e[2] = {F(7), wqkv_ll + 2 * WDD, (int)WDD};
    ca.e[3] = {F(11), wqkv_lh, (int)WDD};
    ca.e[4] = {F(13), wqkv_lh + WDD, (int)WDD};
    ca.e[5] = {F(15), wqkv_lh + 2 * WDD, (int)WDD};
    ca.e[6] = {F(19), wq_cr, (int)WDD};
    ca.e[7] = {F(21), wkv_cr, (int)WDD};
    ca.e[8] = {F(23), wkv_cr + WDD, (int)WDD};
    ca.e[9] = {F(9), wo_ll, (int)WDD};
    ca.e[10] = {F(17), wo_lh, (int)WDD};
    ca.e[11] = {F(25), wo_cr, (int)WDD};
    ca.e[12] = {F(27), wm[0], 1048576};
    ca.e[13] = {F(29), wm[1], 1048576};
    ca.e[14] = {F(31), wm[2], 1048576};
    ca.e[15] = {F(33), wm[3], 1048576};
    k_conv<<<dim3(256, 16), 256, 0, stream>>>(ca);

    CpyArgs cp;
    cp.e[0] = {F(4), bqkv_ll};
    cp.e[1] = {F(6), bqkv_ll + 512};
    cp.e[2] = {F(8), bqkv_ll + 1024};
    cp.e[3] = {F(12), bqkv_lh};
    cp.e[4] = {F(14), bqkv_lh + 512};
    cp.e[5] = {F(16), bqkv_lh + 1024};
    cp.e[6] = {F(22), bkv_cr};
    cp.e[7] = {F(24), bkv_cr + 512};
    k_cpyf<<<dim3(2, 8), 256, 0, stream>>>(cp);

    k_tin<<<dim3(32, 16, 8), dim3(32, 8), 0, stream>>>(LL, LH, ll_s_f, ll_s_b, lh_s_f, lh_s_b);
    k_mask<<<dim3(1024), 256, 0, stream>>>(lh_s_f, raw_tau, kbias);

    auto gp = [&](const u16* A, const u16* W, const float* bias, int N, int K, int nwg) {
        GP g = {};
        g.A = A; g.W = W; g.bias = bias; g.N = N; g.K = K; g.nwg = nwg;
        g.kB = BIG; g.vB = BIG;
        return g;
    };

    // qkv pair (128x128, y selects ll/lh)
    {
        GP a = gp(ll_s_b, wqkv_ll, bqkv_ll, 1536, 512, 384);
        a.kB = 512; a.vB = 1024; a.Qp = Qp; a.Kp = Kp; a.Vt = Vt;
        GP b = gp(lh_s_b, wqkv_lh, bqkv_lh, 1536, 512, 384);
        b.kB = 512; b.vB = 1024; b.Qp = Qp + SET; b.Kp = Kp + SET; b.Vt = Vt + SET;
        k_gemm<128, 128, 0, 1><<<dim3(384, 2), 256, 0, stream>>>(a, b, M);
    }
    // merged self-attention, K-split x2 (1024 blocks) + combine (512 items)
    k_attnK<<<dim3(1024), 256, 0, stream>>>(Qp, Kp, Vt, numW, denW, kbias, 1024);
    k_comb<<<dim3(512), 256, 0, stream>>>(numW, denW, Cxb);
    // wo pair
    {
        GP a = gp(Cxb, wo_ll, F(10), 512, 512, 512);
        a.Cf = ll_o_f; a.Cb = ll_o_b;
        GP b = gp(Cxb + SET, wo_lh, F(18), 512, 512, 512);
        b.Cf = lh_o_f; b.Cb = lh_o_b;
        k_gemm<64, 64, 0, 0><<<dim3(512, 2), 256, 0, stream>>>(a, b, M);
    }
    k_ln<<<dim3(1024), 256, 0, stream>>>(lh_s_f, lh_o_f, nullptr, F(37), F(38), ln_f_lh, ln_b);
    // mlp_lh_up
    {
        GP a = gp(ln_b, wm[2], F(32), 2048, 512, 512);
        a.Cb = hb;
        k_gemm<128, 128, 1, 0><<<dim3(512, 1), 256, 0, stream>>>(a, a, M);
    }
    // crQ + crKV pair
    {
        GP a = gp(ll_o_b, wq_cr, F(20), 512, 512, 512);
        a.Qp = Qp;  // kB=vB=BIG -> all Q (scaled)
        GP b = gp(lh_o_b, wkv_cr, bkv_cr, 1024, 512, 1024);
        b.kB = 0; b.vB = 512; b.Kp = Kp; b.Vt = Vt;
        k_gemm<64, 64, 0, 1><<<dim3(1024, 2), 256, 0, stream>>>(a, b, M);
    }
    // cross attention, K-split x2 (512 blocks) + combine (256 items)
    k_attnK<<<dim3(512), 256, 0, stream>>>(Qp, Kp, Vt, numW, denW, nullptr, 512);
    k_comb<<<dim3(256), 256, 0, stream>>>(numW, denW, Cxb);
    // wo_cr + mlp_lh_down pair
    {
        GP a = gp(Cxb, wo_cr, F(26), 512, 512, 512);
        a.Cf = cr_o_f;
        GP b = gp(hb, wm[3], F(34), 512, 2048, 512);
        b.Cf = yf_lh; b.res = ln_f_lh;
        k_gemm<64, 64, 0, 0><<<dim3(512, 2), 256, 0, stream>>>(a, b, M);
    }
    k_ln<<<dim3(1024), 256, 0, stream>>>(ll_s_f, ll_o_f, cr_o_f, F(35), F(36), ln_f_ll, ln_b);
    // mlp_ll_up
    {
        GP a = gp(ln_b, wm[0], F(28), 2048, 512, 512);
        a.Cb = hb;
        k_gemm<128, 128, 1, 0><<<dim3(512, 1), 256, 0, stream>>>(a, a, M);
    }
    // mlp_ll_down
    {
        GP a = gp(hb, wm[1], F(30), 512, 2048, 512);
        a.Cf = yf_ll; a.res = ln_f_ll;
        k_gemm<64, 64, 0, 0><<<dim3(512, 1), 256, 0, stream>>>(a, a, M);
    }
    k_tout<<<dim3(32, 16, 8), dim3(32, 8), 0, stream>>>(yf_ll, yf_lh, (float*)d_out);
}